// Round 8
// baseline (830.580 us; speedup 1.0000x reference)
//
#include <hip/hip_runtime.h>

typedef float  f4  __attribute__((ext_vector_type(4)));
typedef __bf16 bf8 __attribute__((ext_vector_type(8)));
typedef short  s8  __attribute__((ext_vector_type(8)));
typedef int    i2  __attribute__((ext_vector_type(2)));
typedef double d2v __attribute__((ext_vector_type(2)));

__device__ inline unsigned short f2bf_bits(float f) {
    unsigned u = __float_as_uint(f);
    u += 0x7fffu + ((u >> 16) & 1u);   // RNE to bf16
    return (unsigned short)(u >> 16);
}

// ---------------- W transpose + bf16 convert: Wt[n][k] = bf16(W[k][n]) ----------------
__global__ __launch_bounds__(256) void wtrans_kernel(const float* __restrict__ W,
                                                     unsigned short* __restrict__ Wt) {
    int idx = blockIdx.x * 256 + threadIdx.x;
    if (idx < 768 * 128) {
        int k = idx >> 7, n = idx & 127;
        Wt[n * 768 + k] = f2bf_bits(W[idx]);
    }
}

// ---------------- projection: Out = bf16(l2norm(In @ W + b)), 128-row tiles ----------------
__global__ __launch_bounds__(256) void proj_kernel(const float* __restrict__ In,
                                                   const unsigned short* __restrict__ Wt,
                                                   const float* __restrict__ bias,
                                                   unsigned short* __restrict__ Out) {
    int tid = threadIdx.x;
    int wave = tid >> 6, lane = tid & 63;
    int quad = lane >> 4, rq = lane & 15;
    int rh = (wave >> 1) * 64, ch = (wave & 1) * 64;
    long rowBase = (long)blockIdx.x * 128 + rh;

    f4 acc[4][4];
#pragma unroll
    for (int a = 0; a < 4; ++a)
#pragma unroll
        for (int b = 0; b < 4; ++b) acc[a][b] = 0.0f;

    for (int kc = 0; kc < 24; ++kc) {
        int k0 = kc * 32 + quad * 8;
        bf8 af[4], bfr[4];
#pragma unroll
        for (int t = 0; t < 4; ++t) {
            const float* ap = In + (rowBase + t * 16 + rq) * 768 + k0;
            f4 u0 = *(const f4*)ap;
            f4 u1 = *(const f4*)(ap + 4);
            s8 tmp;
            tmp[0] = (short)f2bf_bits(u0[0]); tmp[1] = (short)f2bf_bits(u0[1]);
            tmp[2] = (short)f2bf_bits(u0[2]); tmp[3] = (short)f2bf_bits(u0[3]);
            tmp[4] = (short)f2bf_bits(u1[0]); tmp[5] = (short)f2bf_bits(u1[1]);
            tmp[6] = (short)f2bf_bits(u1[2]); tmp[7] = (short)f2bf_bits(u1[3]);
            af[t] = __builtin_bit_cast(bf8, tmp);
            bfr[t] = *(const bf8*)(const void*)(Wt + (ch + t * 16 + rq) * 768 + k0);
        }
#pragma unroll
        for (int ti = 0; ti < 4; ++ti)
#pragma unroll
            for (int tj = 0; tj < 4; ++tj)
                acc[ti][tj] = __builtin_amdgcn_mfma_f32_16x16x32_bf16(af[ti], bfr[tj], acc[ti][tj], 0, 0, 0);
    }

    __shared__ float ssq[128];
    if (tid < 128) ssq[tid] = 0.f;
    __syncthreads();

    float b4[4];
#pragma unroll
    for (int tj = 0; tj < 4; ++tj) b4[tj] = bias[ch + tj * 16 + rq];

#pragma unroll
    for (int ti = 0; ti < 4; ++ti)
#pragma unroll
        for (int r = 0; r < 4; ++r) {
            float p = 0.f;
#pragma unroll
            for (int tj = 0; tj < 4; ++tj) {
                float z = acc[ti][tj][r] + b4[tj];
                p += z * z;
            }
            atomicAdd(&ssq[rh + ti * 16 + quad * 4 + r], p);
        }
    __syncthreads();

#pragma unroll
    for (int ti = 0; ti < 4; ++ti)
#pragma unroll
        for (int r = 0; r < 4; ++r) {
            int rowL = rh + ti * 16 + quad * 4 + r;
            float rn = rsqrtf(ssq[rowL]);
#pragma unroll
            for (int tj = 0; tj < 4; ++tj) {
                float z = (acc[ti][tj][r] + b4[tj]) * rn;
                Out[((long)blockIdx.x * 128 + rowL) * 128 + ch + tj * 16 + rq] = f2bf_bits(z);
            }
        }
}

// ------- gram: E[b][i][d=i+j] = bf16(exp((2*dot-2)*10)) = exp(-D/gamma), diagonal stream -------
__global__ __launch_bounds__(256) void gram_kernel(const unsigned short* __restrict__ X,
                                                   const unsigned short* __restrict__ Y,
                                                   unsigned short* __restrict__ S,
                                                   int N, int M, int Nd8) {
    int b = blockIdx.z;
    long i0 = (long)blockIdx.x * 128, j0 = (long)blockIdx.y * 128;
    const unsigned short* Xb = X + (long)b * N * 128;
    const unsigned short* Yb = Y + (long)b * M * 128;
    unsigned short* Sb = S + (long)b * N * Nd8;
    int tid = threadIdx.x, wave = tid >> 6, lane = tid & 63;
    int quad = lane >> 4, rq = lane & 15;
    int rh = (wave >> 1) * 64, ch = (wave & 1) * 64;

    f4 acc[4][4];
#pragma unroll
    for (int a = 0; a < 4; ++a)
#pragma unroll
        for (int c = 0; c < 4; ++c) acc[a][c] = 0.0f;

#pragma unroll
    for (int kc = 0; kc < 4; ++kc) {
        int k0 = kc * 32 + quad * 8;
        bf8 af[4], bfr[4];
#pragma unroll
        for (int t = 0; t < 4; ++t) {
            af[t]  = *(const bf8*)(const void*)(Xb + (i0 + rh + t * 16 + rq) * 128 + k0);
            bfr[t] = *(const bf8*)(const void*)(Yb + (j0 + ch + t * 16 + rq) * 128 + k0);
        }
#pragma unroll
        for (int ti = 0; ti < 4; ++ti)
#pragma unroll
            for (int tj = 0; tj < 4; ++tj)
                acc[ti][tj] = __builtin_amdgcn_mfma_f32_16x16x32_bf16(af[ti], bfr[tj], acc[ti][tj], 0, 0, 0);
    }

#pragma unroll
    for (int ti = 0; ti < 4; ++ti)
#pragma unroll
        for (int r = 0; r < 4; ++r) {
            long gi = i0 + rh + ti * 16 + quad * 4 + r;
#pragma unroll
            for (int tj = 0; tj < 4; ++tj) {
                long gj = j0 + ch + tj * 16 + rq;
                float Ev = __expf(20.0f * acc[ti][tj][r] - 20.0f);
                Sb[gi * Nd8 + gi + gj] = f2bf_bits(Ev);
            }
        }
}

// ---------------- soft-DTW alpha-space DP (fp64) ----------------
// Dual-DP blocks (R7 structure) with the register-budget fix: __launch_bounds__(1024, 4)
// grants 128 VGPR/wave (R7's bare (1024) made the compiler target 64 -> raw[33] spilled,
// WRITE_SIZE 4.6MB of scratch traffic, 2.4x regression). Per-DP protocol VERBATIM R6.
__device__ inline double wshr1_d(double x) {  // lane l <- lane l-1, lane 0 <- 0
    i2 v = __builtin_bit_cast(i2, x);
    v.x = __builtin_amdgcn_update_dpp(0, v.x, 0x138, 0xf, 0xf, false);
    v.y = __builtin_amdgcn_update_dpp(0, v.y, 0x138, 0xf, 0xf, false);
    return __builtin_bit_cast(double, v);
}
#define DPPMAXI(x, ctrl) max((x), __builtin_amdgcn_update_dpp(0, (x), (ctrl), 0xf, 0xf, false))
__device__ inline int redmax64_i(int x) {   // full max in lane 63 (patterns >= 0)
    x = DPPMAXI(x, 0x111);  // row_shr:1
    x = DPPMAXI(x, 0x112);  // row_shr:2
    x = DPPMAXI(x, 0x114);  // row_shr:4
    x = DPPMAXI(x, 0x118);  // row_shr:8
    x = DPPMAXI(x, 0x142);  // row_bcast15
    x = DPPMAXI(x, 0x143);  // row_bcast31
    return x;
}
__device__ inline int hiw(double x) { return __builtin_bit_cast(i2, x).y; }

// K rows/lane PER WAVE; NWAVE active waves per DP; NW = 64*K rows/wave; N = NWAVE*NW.
// w = LOCAL wave id within this DP (0..7); lane = lane id. Waves w >= NWAVE idle.
template<int K, int N, int M, int ND8, int NWAVE>
static __device__ __attribute__((always_inline))
void dp_impl(const unsigned short* __restrict__ E, long batch, int w, int lane,
             float wscale, float* __restrict__ out, char* __restrict__ smem) {
    constexpr int NW    = K * 64;              // rows handled by one wave
    constexpr int BLEN  = NW + M - 1;          // local diag count (odd; BLEN+1 ≡ 0 mod 32)
    constexpr int NCH   = (BLEN + 31) / 32;    // 32-step chunks per wave
    constexpr int BPAD  = NCH * 32;            // = BLEN+1 for all our shapes (1 pad step)
    constexpr int SLEN  = BPAD / 8;            // scale slots (one per 8 boundary entries)
    constexpr int LAG   = NW / 32 + 1;         // chunk lag between adjacent waves
    constexpr int ROUNDS = (NWAVE - 1) * LAG + NCH;

    double* bvAll = (double*)smem;                                  // (NWAVE-1) x BPAD
    int*    scAll = (int*)(smem + (size_t)(NWAVE - 1) * BPAD * 8);  // (NWAVE-1) x SLEN

    const char* Eb = (const char*)(E + batch * N * ND8);
    unsigned off[K];
    uint4 eA[K], eB[K], eC[K], eD[K];
    double vA[K], vB[K];
#pragma unroll
    for (int r = 0; r < K; ++r) {
        off[r] = (unsigned)((((long)(w * NW + K * lane + r)) * ND8 + (long)(w * NW)) * 2);
        vA[r] = 0.0; vB[r] = 0.0;
    }
    int ls = 0;                               // accumulated log2 scale (wave-uniform)

#define EGETV(EQ, PH) __uint_as_float(((PH) & 1) ? ((&(EQ).x)[(PH) >> 1] & 0xffff0000u) \
                                                 : ((&(EQ).x)[(PH) >> 1] << 16))
#define DSTEP(W, P1, EB_, PH, S2, S1) do { \
        double b1 = wshr1_d(P1[K - 1]) + (S1); \
        double b2 = wshr1_d(W[K - 1]) + (S2); \
        double p2 = b2, p1m = b1; \
        _Pragma("unroll") \
        for (int r = 0; r < K; ++r) { \
            double told = W[r]; double c1 = P1[r]; \
            double Ed = (double)EGETV(EB_[r], PH); \
            W[r] = Ed * (p2 + p1m + c1); \
            p2 = told; p1m = c1; \
        } } while (0)

    // pow2 rescale of BOTH live diagonals, anchor 2^870 (biased 1893), every 16 steps.
#define DRESC(W, P1) do { \
        int hm = hiw(W[0]) > hiw(P1[0]) ? hiw(W[0]) : hiw(P1[0]); \
        _Pragma("unroll") \
        for (int r = 1; r < K; ++r) { \
            int h1 = hiw(W[r]), h2 = hiw(P1[r]); \
            if (h1 > hm) hm = h1; if (h2 > hm) hm = h2; } \
        hm = redmax64_i(hm); \
        int hb = __builtin_amdgcn_readlane(hm, 63); \
        if (hb > 0) { \
            int eraw2 = (hb >> 20) & 0x7ff; \
            int sh = 1893 - eraw2; \
            sh = (sh > 1020) ? 1020 : ((sh < -1020) ? -1020 : sh); \
            i2 fb; fb.x = 0; fb.y = (1023 + sh) << 20; \
            double f = __builtin_bit_cast(double, fb); \
            ls += sh; \
            _Pragma("unroll") \
            for (int r = 0; r < K; ++r) { W[r] *= f; P1[r] *= f; } \
        } } while (0)

    // one 8-step group: injections (group frame = current ls), 8 DSTEPs, relay write.
#define GROUP(EX, G) do { \
        double cj[9]; \
        if (w > 0) { \
            _Pragma("unroll") \
            for (int i = 0; i <= 8; ++i) { \
                int jp = 32 * c + 8 * (G) - 1 + i; \
                double v = fmin(ldexp(raw[8 * (G) + i], ls - sc5[(G) + ((6 + i) >> 3)]), 8.9e307); \
                cj[i] = (lane == 0 && jp >= 0 && jp < M) ? v : 0.0; \
            } \
        } else { \
            _Pragma("unroll") \
            for (int i = 0; i <= 8; ++i) cj[i] = 0.0; \
            if ((G) == 0 && c == 0 && lane == 0) cj[0] = 1.0;  /* alpha[-1][-1]=1 seed */ \
        } \
        double bb[8]; \
        DSTEP(vA, vB, EX, 0, cj[0], cj[1]); bb[0] = vA[K - 1]; \
        DSTEP(vB, vA, EX, 1, cj[1], cj[2]); bb[1] = vB[K - 1]; \
        DSTEP(vA, vB, EX, 2, cj[2], cj[3]); bb[2] = vA[K - 1]; \
        DSTEP(vB, vA, EX, 3, cj[3], cj[4]); bb[3] = vB[K - 1]; \
        DSTEP(vA, vB, EX, 4, cj[4], cj[5]); bb[4] = vA[K - 1]; \
        DSTEP(vB, vA, EX, 5, cj[5], cj[6]); bb[5] = vB[K - 1]; \
        DSTEP(vA, vB, EX, 6, cj[6], cj[7]); bb[6] = vA[K - 1]; \
        DSTEP(vB, vA, EX, 7, cj[7], cj[8]); bb[7] = vB[K - 1]; \
        if (w < NWAVE - 1 && lane == 63) { \
            double* bvW = bvAll + (size_t)w * BPAD; \
            int*    scW = scAll + w * SLEN; \
            _Pragma("unroll") \
            for (int i = 0; i < 4; ++i) { \
                d2v p; p.x = bb[2 * i]; p.y = bb[2 * i + 1]; \
                *(d2v*)(bvW + 32 * c + 8 * (G) + 2 * i) = p; \
            } \
            scW[4 * c + (G)] = ls; \
        } } while (0)

    for (int round = 0; round < ROUNDS; ++round) {
        const int c = round - w * LAG;         // this wave's chunk index (wave-uniform)
        if (w < NWAVE && c >= 0 && c < NCH) {
            // ---- boundary raw reads: 33 entries gb..gb+32, gb = NW-2+32c (even, ≡6 mod 8).
            double raw[33]; int sc5[5];
            const int gb = NW - 2 + 32 * c;
            if (w > 0) {
                const double* bvR = bvAll + (size_t)(w - 1) * BPAD;
                const int*    scR = scAll + (w - 1) * SLEN;
#pragma unroll
                for (int i = 0; i < 16; ++i) {
                    int idx = gb + 2 * i; if (idx > BPAD - 2) idx = BPAD - 2;
                    d2v p = *(const d2v*)(bvR + idx);
                    raw[2 * i] = p.x; raw[2 * i + 1] = p.y;
                }
                int idx32 = gb + 32; if (idx32 > BPAD - 1) idx32 = BPAD - 1;
                raw[32] = bvR[idx32];
#pragma unroll
                for (int j = 0; j < 5; ++j) {
                    int s = (gb >> 3) + j; if (s > SLEN - 1) s = SLEN - 1;
                    sc5[j] = scR[s];
                }

                // ---- unified pre-anchor: fold own-field max with incoming injection
                // magnitudes (reader frame), target 2^870. Own field zero (first contact)
                // -> direct ls jump (no multiply; zeros unaffected).
                int hm0 = hiw(vA[0]) > hiw(vB[0]) ? hiw(vA[0]) : hiw(vB[0]);
#pragma unroll
                for (int r = 1; r < K; ++r) {
                    int h1 = hiw(vA[r]), h2 = hiw(vB[r]);
                    if (h1 > hm0) hm0 = h1; if (h2 > hm0) hm0 = h2;
                }
                hm0 = redmax64_i(hm0);
                int hbOwn = __builtin_amdgcn_readlane(hm0, 63);
                int ownEb = (hbOwn > 0) ? (hbOwn >> 20) : -1048576;
                int injEb = -1048576;
#pragma unroll
                for (int i = 0; i <= 32; ++i) {
                    int jp = 32 * c + i - 1;                 // column of raw[i]
                    int er = hiw(raw[i]) >> 20;              // biased exp (values >= 0)
                    int cand = er + (ls - sc5[(6 + i) >> 3]);
                    if (jp >= 0 && jp < M && er > 0 && cand > injEb) injEb = cand;
                }
                int MB = ownEb > injEb ? ownEb : injEb;
                if (MB > -1048576) {
                    int sh = 1893 - MB;
                    if (hbOwn > 0) {
                        sh = (sh > 1020) ? 1020 : ((sh < -1020) ? -1020 : sh);
                        i2 fb; fb.x = 0; fb.y = (1023 + sh) << 20;
                        double f = __builtin_bit_cast(double, fb);
#pragma unroll
                        for (int r = 0; r < K; ++r) { vA[r] *= f; vB[r] *= f; }
                    }
                    ls += sh;
                }
            }
            // ---- E loads: chunk = 32 diag entries = 64 bytes per row (4x uint4)
            if (c == 0) {
#pragma unroll
                for (int r = 0; r < K; ++r) eA[r] = *(const uint4*)(const void*)(Eb + off[r]);
            }
#pragma unroll
            for (int r = 0; r < K; ++r) {
                eB[r] = *(const uint4*)(const void*)(Eb + (off[r] + 16));
                eC[r] = *(const uint4*)(const void*)(Eb + (off[r] + 32));
                eD[r] = *(const uint4*)(const void*)(Eb + (off[r] + 48));
            }

            GROUP(eA, 0);
            GROUP(eB, 1);
            DRESC(vB, vA);
            if (c + 1 < NCH) {
#pragma unroll
                for (int r = 0; r < K; ++r) eA[r] = *(const uint4*)(const void*)(Eb + (off[r] + 64));
            }
            GROUP(eC, 2);
            GROUP(eD, 3);
            DRESC(vB, vA);
#pragma unroll
            for (int r = 0; r < K; ++r) off[r] += 64;
        }
        // publish this round's LDS writes, then sync. Raw s_barrier (no vmcnt drain):
        // in-flight E prefetches survive across the barrier.
        asm volatile("s_waitcnt lgkmcnt(0)\n\ts_barrier" ::: "memory");
    }

    if (w == NWAVE - 1 && lane == 63) {
        // A[N-1][M-1] at last-wave local diag BLEN-1 (even -> vA); the single pad step
        // (odd) scribbles vB only. Row N-1 = lane 63, r = K-1.
        double v = vA[K - 1];
        i2 vb2 = __builtin_bit_cast(i2, v);
        int eraw = (vb2.y >> 20) & 0x7ff;
        int ex = eraw - 1022;                       // v = m * 2^ex, m in [0.5,1)
        i2 mb; mb.x = vb2.x; mb.y = (vb2.y & 0x000FFFFF) | (1022 << 20);
        float mf = (float)__builtin_bit_cast(double, mb);
        if (!(mf > 0.f)) mf = 0.5f;                 // guard (cannot happen if DP sane)
        double R = -0.1 * ((double)logf(mf) + (double)(ex - ls) * 0.6931471805599453);
        atomicAdd(out, wscale * (float)R);
    }
#undef DSTEP
#undef DRESC
#undef GROUP
#undef EGETV
}

__global__ __launch_bounds__(1024, 4) void dp_kernel(const unsigned short* __restrict__ Sxy,
                                                     const unsigned short* __restrict__ Sxx,
                                                     const unsigned short* __restrict__ Syy,
                                                     float* __restrict__ out) {
    // two DP regions; max per-DP = Sxx: 7 x (1152 dbl + 144 int) = 68544 B -> 137088 B
    // (< 160 KiB gfx950 LDS/workgroup; forces 1 block/CU = 4 waves/SIMD).
    // launch_bounds(1024, 4): 16 waves resident = 4/SIMD -> 128 VGPR budget (no spill).
    __shared__ __attribute__((aligned(16))) char smem[137088];
    const int wv   = threadIdx.x >> 6;        // 0..15
    const int lane = threadIdx.x & 63;
    const int half = wv >> 3;                 // 0 or 1: which DP in this block
    const int wloc = wv & 7;                  // local wave id within the DP
    const long b   = (long)blockIdx.x * 2 + half;
    char* sm = smem + half * 68544;
    if (blockIdx.y == 0)      dp_impl<2, 1024,  768, 1792, 8>(Sxy, b, wloc, lane,  1.0f / 28672.0f, out, sm);
    else if (blockIdx.y == 1) dp_impl<2, 1024, 1024, 2048, 8>(Sxx, b, wloc, lane, -0.5f / 28672.0f, out, sm);
    else                      dp_impl<2,  768,  768, 1536, 6>(Syy, b, wloc, lane, -0.5f / 28672.0f, out, sm);
}

// ---------------- host launcher ----------------
extern "C" void kernel_launch(void* const* d_in, const int* in_sizes, int n_in,
                              void* d_out, int out_size, void* d_ws, size_t ws_size,
                              hipStream_t stream) {
    (void)in_sizes; (void)n_in; (void)out_size; (void)ws_size;
    const float* feats = (const float*)d_in[0];   // [16,1024,768]
    const float* targ  = (const float*)d_in[1];   // [16,768,768]
    const float* W     = (const float*)d_in[2];   // [768,128]
    const float* bias  = (const float*)d_in[3];   // [128]

    char* ws = (char*)d_ws;
    unsigned short* xbf = (unsigned short*)(ws + 0);            // 16384x128 bf16 = 4 MB
    unsigned short* ybf = (unsigned short*)(ws + 4194304);      // 12288x128 bf16 = 3 MB
    unsigned short* Wt  = (unsigned short*)(ws + 7340032);      // 128x768 bf16
    unsigned short* SxyE = (unsigned short*)(ws + 7536640);     // 16x1024x1792 bf16 E
    unsigned short* SxxE = (unsigned short*)(ws + 66256896);    // 16x1024x2048 bf16 E
    unsigned short* SyyE = (unsigned short*)(ws + 133365760);   // 16x768x1536  bf16 E

    hipMemsetAsync(d_out, 0, sizeof(float), stream);
    // zero all E streams so pad cells (invalid j) are E=0 -> alpha=0 automatically
    hipMemsetAsync(ws + 7536640, 0, 163577856, stream);

    wtrans_kernel<<<384, 256, 0, stream>>>(W, Wt);
    proj_kernel<<<128, 256, 0, stream>>>(feats, Wt, bias, xbf);
    proj_kernel<<<96, 256, 0, stream>>>(targ, Wt, bias, ybf);

    gram_kernel<<<dim3(8, 6, 16), 256, 0, stream>>>(xbf, ybf, SxyE, 1024,  768, 1792);
    gram_kernel<<<dim3(8, 8, 16), 256, 0, stream>>>(xbf, xbf, SxxE, 1024, 1024, 2048);
    gram_kernel<<<dim3(6, 6, 16), 256, 0, stream>>>(ybf, ybf, SyyE,  768,  768, 1536);

    // dual-DP blocks: 1024 threads = two 8-wave pipelines (batches 2bx, 2bx+1)
    dp_kernel<<<dim3(8, 3), 1024, 0, stream>>>(SxyE, SxxE, SyyE, (float*)d_out);
}

// Round 9
// 684.222 us; speedup vs baseline: 1.2139x; 1.2139x over previous
//
#include <hip/hip_runtime.h>

typedef float  f4  __attribute__((ext_vector_type(4)));
typedef __bf16 bf8 __attribute__((ext_vector_type(8)));
typedef short  s8  __attribute__((ext_vector_type(8)));
typedef int    i2  __attribute__((ext_vector_type(2)));
typedef double d2v __attribute__((ext_vector_type(2)));

__device__ inline unsigned short f2bf_bits(float f) {
    unsigned u = __float_as_uint(f);
    u += 0x7fffu + ((u >> 16) & 1u);   // RNE to bf16
    return (unsigned short)(u >> 16);
}

// ---------------- W transpose + bf16 convert: Wt[n][k] = bf16(W[k][n]) ----------------
__global__ __launch_bounds__(256) void wtrans_kernel(const float* __restrict__ W,
                                                     unsigned short* __restrict__ Wt) {
    int idx = blockIdx.x * 256 + threadIdx.x;
    if (idx < 768 * 128) {
        int k = idx >> 7, n = idx & 127;
        Wt[n * 768 + k] = f2bf_bits(W[idx]);
    }
}

// ---------------- projection: Out = bf16(l2norm(In @ W + b)), 128-row tiles ----------------
__global__ __launch_bounds__(256) void proj_kernel(const float* __restrict__ In,
                                                   const unsigned short* __restrict__ Wt,
                                                   const float* __restrict__ bias,
                                                   unsigned short* __restrict__ Out) {
    int tid = threadIdx.x;
    int wave = tid >> 6, lane = tid & 63;
    int quad = lane >> 4, rq = lane & 15;
    int rh = (wave >> 1) * 64, ch = (wave & 1) * 64;
    long rowBase = (long)blockIdx.x * 128 + rh;

    f4 acc[4][4];
#pragma unroll
    for (int a = 0; a < 4; ++a)
#pragma unroll
        for (int b = 0; b < 4; ++b) acc[a][b] = 0.0f;

    for (int kc = 0; kc < 24; ++kc) {
        int k0 = kc * 32 + quad * 8;
        bf8 af[4], bfr[4];
#pragma unroll
        for (int t = 0; t < 4; ++t) {
            const float* ap = In + (rowBase + t * 16 + rq) * 768 + k0;
            f4 u0 = *(const f4*)ap;
            f4 u1 = *(const f4*)(ap + 4);
            s8 tmp;
            tmp[0] = (short)f2bf_bits(u0[0]); tmp[1] = (short)f2bf_bits(u0[1]);
            tmp[2] = (short)f2bf_bits(u0[2]); tmp[3] = (short)f2bf_bits(u0[3]);
            tmp[4] = (short)f2bf_bits(u1[0]); tmp[5] = (short)f2bf_bits(u1[1]);
            tmp[6] = (short)f2bf_bits(u1[2]); tmp[7] = (short)f2bf_bits(u1[3]);
            af[t] = __builtin_bit_cast(bf8, tmp);
            bfr[t] = *(const bf8*)(const void*)(Wt + (ch + t * 16 + rq) * 768 + k0);
        }
#pragma unroll
        for (int ti = 0; ti < 4; ++ti)
#pragma unroll
            for (int tj = 0; tj < 4; ++tj)
                acc[ti][tj] = __builtin_amdgcn_mfma_f32_16x16x32_bf16(af[ti], bfr[tj], acc[ti][tj], 0, 0, 0);
    }

    __shared__ float ssq[128];
    if (tid < 128) ssq[tid] = 0.f;
    __syncthreads();

    float b4[4];
#pragma unroll
    for (int tj = 0; tj < 4; ++tj) b4[tj] = bias[ch + tj * 16 + rq];

#pragma unroll
    for (int ti = 0; ti < 4; ++ti)
#pragma unroll
        for (int r = 0; r < 4; ++r) {
            float p = 0.f;
#pragma unroll
            for (int tj = 0; tj < 4; ++tj) {
                float z = acc[ti][tj][r] + b4[tj];
                p += z * z;
            }
            atomicAdd(&ssq[rh + ti * 16 + quad * 4 + r], p);
        }
    __syncthreads();

#pragma unroll
    for (int ti = 0; ti < 4; ++ti)
#pragma unroll
        for (int r = 0; r < 4; ++r) {
            int rowL = rh + ti * 16 + quad * 4 + r;
            float rn = rsqrtf(ssq[rowL]);
#pragma unroll
            for (int tj = 0; tj < 4; ++tj) {
                float z = (acc[ti][tj][r] + b4[tj]) * rn;
                Out[((long)blockIdx.x * 128 + rowL) * 128 + ch + tj * 16 + rq] = f2bf_bits(z);
            }
        }
}

// ------- gram: E[b][i][d=i+j] = bf16(exp((2*dot-2)*10)) = exp(-D/gamma), diagonal stream -------
__global__ __launch_bounds__(256) void gram_kernel(const unsigned short* __restrict__ X,
                                                   const unsigned short* __restrict__ Y,
                                                   unsigned short* __restrict__ S,
                                                   int N, int M, int Nd8) {
    int b = blockIdx.z;
    long i0 = (long)blockIdx.x * 128, j0 = (long)blockIdx.y * 128;
    const unsigned short* Xb = X + (long)b * N * 128;
    const unsigned short* Yb = Y + (long)b * M * 128;
    unsigned short* Sb = S + (long)b * N * Nd8;
    int tid = threadIdx.x, wave = tid >> 6, lane = tid & 63;
    int quad = lane >> 4, rq = lane & 15;
    int rh = (wave >> 1) * 64, ch = (wave & 1) * 64;

    f4 acc[4][4];
#pragma unroll
    for (int a = 0; a < 4; ++a)
#pragma unroll
        for (int c = 0; c < 4; ++c) acc[a][c] = 0.0f;

#pragma unroll
    for (int kc = 0; kc < 4; ++kc) {
        int k0 = kc * 32 + quad * 8;
        bf8 af[4], bfr[4];
#pragma unroll
        for (int t = 0; t < 4; ++t) {
            af[t]  = *(const bf8*)(const void*)(Xb + (i0 + rh + t * 16 + rq) * 128 + k0);
            bfr[t] = *(const bf8*)(const void*)(Yb + (j0 + ch + t * 16 + rq) * 128 + k0);
        }
#pragma unroll
        for (int ti = 0; ti < 4; ++ti)
#pragma unroll
            for (int tj = 0; tj < 4; ++tj)
                acc[ti][tj] = __builtin_amdgcn_mfma_f32_16x16x32_bf16(af[ti], bfr[tj], acc[ti][tj], 0, 0, 0);
    }

#pragma unroll
    for (int ti = 0; ti < 4; ++ti)
#pragma unroll
        for (int r = 0; r < 4; ++r) {
            long gi = i0 + rh + ti * 16 + quad * 4 + r;
#pragma unroll
            for (int tj = 0; tj < 4; ++tj) {
                long gj = j0 + ch + tj * 16 + rq;
                float Ev = __expf(20.0f * acc[ti][tj][r] - 20.0f);
                Sb[gi * Nd8 + gi + gj] = f2bf_bits(Ev);
            }
        }
}

// ---------------- soft-DTW alpha-space DP (fp64) ----------------
// Dual-DP 1024-thread blocks (two 8-wave pipelines per CU = 4 waves/SIMD).
// Anti-spill round: (1) amdgpu_waves_per_eu(4,4) caps max occupancy -> VGPR budget
// 512/4 = 128 (launch_bounds' 2nd arg only raises the MIN, which is why R8 was inert);
// (2) register-demand cut with identical semantics: raw[33] removed (pre-anchor scan
// uses rolling max over LDS pair reads; GROUP injections read LDS lazily -- race-safe,
// producer wave writes >= 2 entries / 1 slot beyond our read window), bb[8] removed
// (relay pairs stored right after each odd step), cj[9] -> rolling window.
__device__ inline double wshr1_d(double x) {  // lane l <- lane l-1, lane 0 <- 0
    i2 v = __builtin_bit_cast(i2, x);
    v.x = __builtin_amdgcn_update_dpp(0, v.x, 0x138, 0xf, 0xf, false);
    v.y = __builtin_amdgcn_update_dpp(0, v.y, 0x138, 0xf, 0xf, false);
    return __builtin_bit_cast(double, v);
}
#define DPPMAXI(x, ctrl) max((x), __builtin_amdgcn_update_dpp(0, (x), (ctrl), 0xf, 0xf, false))
__device__ inline int redmax64_i(int x) {   // full max in lane 63 (patterns >= 0)
    x = DPPMAXI(x, 0x111);  // row_shr:1
    x = DPPMAXI(x, 0x112);  // row_shr:2
    x = DPPMAXI(x, 0x114);  // row_shr:4
    x = DPPMAXI(x, 0x118);  // row_shr:8
    x = DPPMAXI(x, 0x142);  // row_bcast15
    x = DPPMAXI(x, 0x143);  // row_bcast31
    return x;
}
__device__ inline int hiw(double x) { return __builtin_bit_cast(i2, x).y; }

// K rows/lane PER WAVE; NWAVE active waves per DP; NW = 64*K rows/wave; N = NWAVE*NW.
// w = LOCAL wave id within this DP (0..7); lane = lane id. Waves w >= NWAVE idle.
template<int K, int N, int M, int ND8, int NWAVE>
static __device__ __attribute__((always_inline))
void dp_impl(const unsigned short* __restrict__ E, long batch, int w, int lane,
             float wscale, float* __restrict__ out, char* __restrict__ smem) {
    constexpr int NW    = K * 64;              // rows handled by one wave
    constexpr int BLEN  = NW + M - 1;          // local diag count (odd; BLEN+1 ≡ 0 mod 32)
    constexpr int NCH   = (BLEN + 31) / 32;    // 32-step chunks per wave
    constexpr int BPAD  = NCH * 32;            // = BLEN+1 for all our shapes (1 pad step)
    constexpr int SLEN  = BPAD / 8;            // scale slots (one per 8 boundary entries)
    constexpr int LAG   = NW / 32 + 1;         // chunk lag between adjacent waves
    constexpr int ROUNDS = (NWAVE - 1) * LAG + NCH;

    double* bvAll = (double*)smem;                                  // (NWAVE-1) x BPAD
    int*    scAll = (int*)(smem + (size_t)(NWAVE - 1) * BPAD * 8);  // (NWAVE-1) x SLEN
    const double* bvR = bvAll + (size_t)(w > 0 ? w - 1 : 0) * BPAD;
    const int*    scR = scAll + (size_t)(w > 0 ? w - 1 : 0) * SLEN;
    double* bvW = bvAll + (size_t)(w < NWAVE - 1 ? w : 0) * BPAD;   // deref'd only if w<NWAVE-1
    int*    scW = scAll + (size_t)(w < NWAVE - 1 ? w : 0) * SLEN;

    const char* Eb = (const char*)(E + batch * N * ND8);
    unsigned off[K];
    uint4 eA[K], eB[K], eC[K], eD[K];
    double vA[K], vB[K];
#pragma unroll
    for (int r = 0; r < K; ++r) {
        off[r] = (unsigned)((((long)(w * NW + K * lane + r)) * ND8 + (long)(w * NW)) * 2);
        vA[r] = 0.0; vB[r] = 0.0;
    }
    int ls = 0;                               // accumulated log2 scale (wave-uniform)

#define EGETV(EQ, PH) __uint_as_float(((PH) & 1) ? ((&(EQ).x)[(PH) >> 1] & 0xffff0000u) \
                                                 : ((&(EQ).x)[(PH) >> 1] << 16))
#define DSTEP(W, P1, EB_, PH, S2, S1) do { \
        double b1 = wshr1_d(P1[K - 1]) + (S1); \
        double b2 = wshr1_d(W[K - 1]) + (S2); \
        double p2 = b2, p1m = b1; \
        _Pragma("unroll") \
        for (int r = 0; r < K; ++r) { \
            double told = W[r]; double c1 = P1[r]; \
            double Ed = (double)EGETV(EB_[r], PH); \
            W[r] = Ed * (p2 + p1m + c1); \
            p2 = told; p1m = c1; \
        } } while (0)

    // pow2 rescale of BOTH live diagonals, anchor 2^870 (biased 1893), every 16 steps.
#define DRESC(W, P1) do { \
        int hm = hiw(W[0]) > hiw(P1[0]) ? hiw(W[0]) : hiw(P1[0]); \
        _Pragma("unroll") \
        for (int r = 1; r < K; ++r) { \
            int h1 = hiw(W[r]), h2 = hiw(P1[r]); \
            if (h1 > hm) hm = h1; if (h2 > hm) hm = h2; } \
        hm = redmax64_i(hm); \
        int hb = __builtin_amdgcn_readlane(hm, 63); \
        if (hb > 0) { \
            int eraw2 = (hb >> 20) & 0x7ff; \
            int sh = 1893 - eraw2; \
            sh = (sh > 1020) ? 1020 : ((sh < -1020) ? -1020 : sh); \
            i2 fb; fb.x = 0; fb.y = (1023 + sh) << 20; \
            double f = __builtin_bit_cast(double, fb); \
            ls += sh; \
            _Pragma("unroll") \
            for (int r = 0; r < K; ++r) { W[r] *= f; P1[r] *= f; } \
        } } while (0)

    // lazy boundary reads (clamped like the bulk loads; clamped entries are column-masked)
#define LDP(k)  (*(const d2v*)(bvR + ((gb + (k) > BPAD - 2) ? (BPAD - 2) : (gb + (k)))))
#define LDS1(k) (bvR[(gb + (k) > BPAD - 1) ? (BPAD - 1) : (gb + (k))])
    // injection i of group G: stored_r = raw * 2^(ls_r - ls_w), masked; w0 gets the DP seed
#define INJE(G_, i_, rv) \
    (w > 0 ? ((lane == 0 && (32 * c + 8 * (G_) - 1 + (i_)) >= 0 \
                        && (32 * c + 8 * (G_) - 1 + (i_)) < M) \
                ? fmin(ldexp((rv), ls - sc5[(G_) + ((6 + (i_)) >> 3)]), 8.9e307) : 0.0) \
           : ((c == 0 && (G_) == 0 && (i_) == 0 && lane == 0) ? 1.0 : 0.0))
    // relay-pair store (entries 8G+2t, 8G+2t+1), issued right after the odd step
#define WBP(G_, t_, v0, v1) do { \
        if (w < NWAVE - 1 && lane == 63) { \
            d2v zp; zp.x = (v0); zp.y = (v1); \
            *(d2v*)(bvW + 32 * c + 8 * (G_) + 2 * (t_)) = zp; \
        } } while (0)

    // one 8-step group: lazy LDS injections (rolling window), 8 DSTEPs, interleaved relay
#define GROUP(EX, G) do { \
        d2v p01 = LDP(8 * (G) + 0); \
        d2v p23 = LDP(8 * (G) + 2); \
        double a0 = INJE(G, 0, p01.x), a1 = INJE(G, 1, p01.y); \
        double bw; \
        DSTEP(vA, vB, EX, 0, a0, a1); bw = vA[K - 1]; \
        double a2 = INJE(G, 2, p23.x), a3 = INJE(G, 3, p23.y); \
        DSTEP(vB, vA, EX, 1, a1, a2); WBP(G, 0, bw, vB[K - 1]); \
        d2v p45 = LDP(8 * (G) + 4); \
        DSTEP(vA, vB, EX, 2, a2, a3); bw = vA[K - 1]; \
        double a4 = INJE(G, 4, p45.x), a5 = INJE(G, 5, p45.y); \
        DSTEP(vB, vA, EX, 3, a3, a4); WBP(G, 1, bw, vB[K - 1]); \
        d2v p67 = LDP(8 * (G) + 6); \
        DSTEP(vA, vB, EX, 4, a4, a5); bw = vA[K - 1]; \
        double a6 = INJE(G, 6, p67.x), a7 = INJE(G, 7, p67.y); \
        DSTEP(vB, vA, EX, 5, a5, a6); WBP(G, 2, bw, vB[K - 1]); \
        double p8 = LDS1(8 * (G) + 8); \
        DSTEP(vA, vB, EX, 6, a6, a7); bw = vA[K - 1]; \
        double a8 = INJE(G, 8, p8); \
        DSTEP(vB, vA, EX, 7, a7, a8); WBP(G, 3, bw, vB[K - 1]); \
        if (w < NWAVE - 1 && lane == 63) scW[4 * c + (G)] = ls; \
    } while (0)

    for (int round = 0; round < ROUNDS; ++round) {
        const int c = round - w * LAG;         // this wave's chunk index (wave-uniform)
        if (w < NWAVE && c >= 0 && c < NCH) {
            const int gb = NW - 2 + 32 * c;    // first boundary entry (even, ≡6 mod 8)
            int sc5[5] = {0, 0, 0, 0, 0};
            if (w > 0) {
#pragma unroll
                for (int j = 0; j < 5; ++j) {
                    int s = (gb >> 3) + j; if (s > SLEN - 1) s = SLEN - 1;
                    sc5[j] = scR[s];
                }
                // ---- unified pre-anchor: fold own-field max with incoming injection
                // magnitudes (reader frame), target 2^870. Rolling max, no raw[] array.
                int hm0 = hiw(vA[0]) > hiw(vB[0]) ? hiw(vA[0]) : hiw(vB[0]);
#pragma unroll
                for (int r = 1; r < K; ++r) {
                    int h1 = hiw(vA[r]), h2 = hiw(vB[r]);
                    if (h1 > hm0) hm0 = h1; if (h2 > hm0) hm0 = h2;
                }
                hm0 = redmax64_i(hm0);
                int hbOwn = __builtin_amdgcn_readlane(hm0, 63);
                int ownEb = (hbOwn > 0) ? (hbOwn >> 20) : -1048576;
                int injEb = -1048576;
#pragma unroll
                for (int t = 0; t < 16; ++t) {
                    int idx = gb + 2 * t; if (idx > BPAD - 2) idx = BPAD - 2;
                    d2v pp = *(const d2v*)(bvR + idx);
                    int jp0 = 32 * c + 2 * t - 1, jp1 = jp0 + 1;
                    int er0 = hiw(pp.x) >> 20, er1 = hiw(pp.y) >> 20;
                    int cd0 = er0 + (ls - sc5[(6 + 2 * t) >> 3]);
                    int cd1 = er1 + (ls - sc5[(7 + 2 * t) >> 3]);
                    if (jp0 >= 0 && jp0 < M && er0 > 0 && cd0 > injEb) injEb = cd0;
                    if (jp1 >= 0 && jp1 < M && er1 > 0 && cd1 > injEb) injEb = cd1;
                }
                {
                    int idx = gb + 32; if (idx > BPAD - 1) idx = BPAD - 1;
                    double rv = bvR[idx];
                    int jp = 32 * c + 31; int er = hiw(rv) >> 20;
                    int cd = er + (ls - sc5[4]);
                    if (jp < M && er > 0 && cd > injEb) injEb = cd;
                }
                int MB = ownEb > injEb ? ownEb : injEb;
                if (MB > -1048576) {
                    int sh = 1893 - MB;
                    if (hbOwn > 0) {
                        sh = (sh > 1020) ? 1020 : ((sh < -1020) ? -1020 : sh);
                        i2 fb; fb.x = 0; fb.y = (1023 + sh) << 20;
                        double f = __builtin_bit_cast(double, fb);
#pragma unroll
                        for (int r = 0; r < K; ++r) { vA[r] *= f; vB[r] *= f; }
                    }
                    ls += sh;
                }
            }
            // ---- E loads: chunk = 32 diag entries = 64 bytes per row (4x uint4)
            if (c == 0) {
#pragma unroll
                for (int r = 0; r < K; ++r) eA[r] = *(const uint4*)(const void*)(Eb + off[r]);
            }
#pragma unroll
            for (int r = 0; r < K; ++r) {
                eB[r] = *(const uint4*)(const void*)(Eb + (off[r] + 16));
                eC[r] = *(const uint4*)(const void*)(Eb + (off[r] + 32));
                eD[r] = *(const uint4*)(const void*)(Eb + (off[r] + 48));
            }

            GROUP(eA, 0);
            GROUP(eB, 1);
            DRESC(vB, vA);
            if (c + 1 < NCH) {
#pragma unroll
                for (int r = 0; r < K; ++r) eA[r] = *(const uint4*)(const void*)(Eb + (off[r] + 64));
            }
            GROUP(eC, 2);
            GROUP(eD, 3);
            DRESC(vB, vA);
#pragma unroll
            for (int r = 0; r < K; ++r) off[r] += 64;
        }
        // publish this round's LDS writes, then sync. Raw s_barrier (no vmcnt drain):
        // in-flight E prefetches survive across the barrier.
        asm volatile("s_waitcnt lgkmcnt(0)\n\ts_barrier" ::: "memory");
    }

    if (w == NWAVE - 1 && lane == 63) {
        // A[N-1][M-1] at last-wave local diag BLEN-1 (even -> vA); the single pad step
        // (odd) scribbles vB only. Row N-1 = lane 63, r = K-1.
        double v = vA[K - 1];
        i2 vb2 = __builtin_bit_cast(i2, v);
        int eraw = (vb2.y >> 20) & 0x7ff;
        int ex = eraw - 1022;                       // v = m * 2^ex, m in [0.5,1)
        i2 mb; mb.x = vb2.x; mb.y = (vb2.y & 0x000FFFFF) | (1022 << 20);
        float mf = (float)__builtin_bit_cast(double, mb);
        if (!(mf > 0.f)) mf = 0.5f;                 // guard (cannot happen if DP sane)
        double R = -0.1 * ((double)logf(mf) + (double)(ex - ls) * 0.6931471805599453);
        atomicAdd(out, wscale * (float)R);
    }
#undef DSTEP
#undef DRESC
#undef GROUP
#undef WBP
#undef INJE
#undef LDP
#undef LDS1
#undef EGETV
}

__global__ __launch_bounds__(1024)
__attribute__((amdgpu_waves_per_eu(4, 4)))
void dp_kernel(const unsigned short* __restrict__ Sxy,
               const unsigned short* __restrict__ Sxx,
               const unsigned short* __restrict__ Syy,
               float* __restrict__ out) {
    // two DP regions; max per-DP = Sxx: 7 x (1152 dbl + 144 int) = 68544 B -> 137088 B
    // (< 160 KiB gfx950 LDS/workgroup; forces 1 block/CU = 4 waves/SIMD).
    // amdgpu_waves_per_eu(4,4): caps max occupancy at 4 waves/EU -> VGPR budget 128.
    __shared__ __attribute__((aligned(16))) char smem[137088];
    const int wv   = threadIdx.x >> 6;        // 0..15
    const int lane = threadIdx.x & 63;
    const int half = wv >> 3;                 // 0 or 1: which DP in this block
    const int wloc = wv & 7;                  // local wave id within the DP
    const long b   = (long)blockIdx.x * 2 + half;
    char* sm = smem + half * 68544;
    if (blockIdx.y == 0)      dp_impl<2, 1024,  768, 1792, 8>(Sxy, b, wloc, lane,  1.0f / 28672.0f, out, sm);
    else if (blockIdx.y == 1) dp_impl<2, 1024, 1024, 2048, 8>(Sxx, b, wloc, lane, -0.5f / 28672.0f, out, sm);
    else                      dp_impl<2,  768,  768, 1536, 6>(Syy, b, wloc, lane, -0.5f / 28672.0f, out, sm);
}

// ---------------- host launcher ----------------
extern "C" void kernel_launch(void* const* d_in, const int* in_sizes, int n_in,
                              void* d_out, int out_size, void* d_ws, size_t ws_size,
                              hipStream_t stream) {
    (void)in_sizes; (void)n_in; (void)out_size; (void)ws_size;
    const float* feats = (const float*)d_in[0];   // [16,1024,768]
    const float* targ  = (const float*)d_in[1];   // [16,768,768]
    const float* W     = (const float*)d_in[2];   // [768,128]
    const float* bias  = (const float*)d_in[3];   // [128]

    char* ws = (char*)d_ws;
    unsigned short* xbf = (unsigned short*)(ws + 0);            // 16384x128 bf16 = 4 MB
    unsigned short* ybf = (unsigned short*)(ws + 4194304);      // 12288x128 bf16 = 3 MB
    unsigned short* Wt  = (unsigned short*)(ws + 7340032);      // 128x768 bf16
    unsigned short* SxyE = (unsigned short*)(ws + 7536640);     // 16x1024x1792 bf16 E
    unsigned short* SxxE = (unsigned short*)(ws + 66256896);    // 16x1024x2048 bf16 E
    unsigned short* SyyE = (unsigned short*)(ws + 133365760);   // 16x768x1536  bf16 E

    hipMemsetAsync(d_out, 0, sizeof(float), stream);
    // zero all E streams so pad cells (invalid j) are E=0 -> alpha=0 automatically
    hipMemsetAsync(ws + 7536640, 0, 163577856, stream);

    wtrans_kernel<<<384, 256, 0, stream>>>(W, Wt);
    proj_kernel<<<128, 256, 0, stream>>>(feats, Wt, bias, xbf);
    proj_kernel<<<96, 256, 0, stream>>>(targ, Wt, bias, ybf);

    gram_kernel<<<dim3(8, 6, 16), 256, 0, stream>>>(xbf, ybf, SxyE, 1024,  768, 1792);
    gram_kernel<<<dim3(8, 8, 16), 256, 0, stream>>>(xbf, xbf, SxxE, 1024, 1024, 2048);
    gram_kernel<<<dim3(6, 6, 16), 256, 0, stream>>>(ybf, ybf, SyyE,  768,  768, 1536);

    // dual-DP blocks: 1024 threads = two 8-wave pipelines (batches 2bx, 2bx+1)
    dp_kernel<<<dim3(8, 3), 1024, 0, stream>>>(SxyE, SxxE, SyyE, (float*)d_out);
}

// Round 11
// 586.343 us; speedup vs baseline: 1.4165x; 1.1669x over previous
//
#include <hip/hip_runtime.h>

typedef float  f4  __attribute__((ext_vector_type(4)));
typedef __bf16 bf8 __attribute__((ext_vector_type(8)));
typedef short  s8  __attribute__((ext_vector_type(8)));
typedef int    i2  __attribute__((ext_vector_type(2)));
typedef double d2v __attribute__((ext_vector_type(2)));

__device__ inline unsigned short f2bf_bits(float f) {
    unsigned u = __float_as_uint(f);
    u += 0x7fffu + ((u >> 16) & 1u);   // RNE to bf16
    return (unsigned short)(u >> 16);
}

// ---------------- W transpose + bf16 convert: Wt[n][k] = bf16(W[k][n]) ----------------
__global__ __launch_bounds__(256) void wtrans_kernel(const float* __restrict__ W,
                                                     unsigned short* __restrict__ Wt) {
    int idx = blockIdx.x * 256 + threadIdx.x;
    if (idx < 768 * 128) {
        int k = idx >> 7, n = idx & 127;
        Wt[n * 768 + k] = f2bf_bits(W[idx]);
    }
}

// ---------------- projection: Out = bf16(l2norm(In @ W + b)), 128-row tiles ----------------
__global__ __launch_bounds__(256) void proj_kernel(const float* __restrict__ In,
                                                   const unsigned short* __restrict__ Wt,
                                                   const float* __restrict__ bias,
                                                   unsigned short* __restrict__ Out) {
    int tid = threadIdx.x;
    int wave = tid >> 6, lane = tid & 63;
    int quad = lane >> 4, rq = lane & 15;
    int rh = (wave >> 1) * 64, ch = (wave & 1) * 64;
    long rowBase = (long)blockIdx.x * 128 + rh;

    f4 acc[4][4];
#pragma unroll
    for (int a = 0; a < 4; ++a)
#pragma unroll
        for (int b = 0; b < 4; ++b) acc[a][b] = 0.0f;

    for (int kc = 0; kc < 24; ++kc) {
        int k0 = kc * 32 + quad * 8;
        bf8 af[4], bfr[4];
#pragma unroll
        for (int t = 0; t < 4; ++t) {
            const float* ap = In + (rowBase + t * 16 + rq) * 768 + k0;
            f4 u0 = *(const f4*)ap;
            f4 u1 = *(const f4*)(ap + 4);
            s8 tmp;
            tmp[0] = (short)f2bf_bits(u0[0]); tmp[1] = (short)f2bf_bits(u0[1]);
            tmp[2] = (short)f2bf_bits(u0[2]); tmp[3] = (short)f2bf_bits(u0[3]);
            tmp[4] = (short)f2bf_bits(u1[0]); tmp[5] = (short)f2bf_bits(u1[1]);
            tmp[6] = (short)f2bf_bits(u1[2]); tmp[7] = (short)f2bf_bits(u1[3]);
            af[t] = __builtin_bit_cast(bf8, tmp);
            bfr[t] = *(const bf8*)(const void*)(Wt + (ch + t * 16 + rq) * 768 + k0);
        }
#pragma unroll
        for (int ti = 0; ti < 4; ++ti)
#pragma unroll
            for (int tj = 0; tj < 4; ++tj)
                acc[ti][tj] = __builtin_amdgcn_mfma_f32_16x16x32_bf16(af[ti], bfr[tj], acc[ti][tj], 0, 0, 0);
    }

    __shared__ float ssq[128];
    if (tid < 128) ssq[tid] = 0.f;
    __syncthreads();

    float b4[4];
#pragma unroll
    for (int tj = 0; tj < 4; ++tj) b4[tj] = bias[ch + tj * 16 + rq];

#pragma unroll
    for (int ti = 0; ti < 4; ++ti)
#pragma unroll
        for (int r = 0; r < 4; ++r) {
            float p = 0.f;
#pragma unroll
            for (int tj = 0; tj < 4; ++tj) {
                float z = acc[ti][tj][r] + b4[tj];
                p += z * z;
            }
            atomicAdd(&ssq[rh + ti * 16 + quad * 4 + r], p);
        }
    __syncthreads();

#pragma unroll
    for (int ti = 0; ti < 4; ++ti)
#pragma unroll
        for (int r = 0; r < 4; ++r) {
            int rowL = rh + ti * 16 + quad * 4 + r;
            float rn = rsqrtf(ssq[rowL]);
#pragma unroll
            for (int tj = 0; tj < 4; ++tj) {
                float z = (acc[ti][tj][r] + b4[tj]) * rn;
                Out[((long)blockIdx.x * 128 + rowL) * 128 + ch + tj * 16 + rq] = f2bf_bits(z);
            }
        }
}

// ------- gram: E[b][i][d=i+j] = bf16(exp((2*dot-2)*10)) = exp(-D/gamma), diagonal stream -------
__global__ __launch_bounds__(256) void gram_kernel(const unsigned short* __restrict__ X,
                                                   const unsigned short* __restrict__ Y,
                                                   unsigned short* __restrict__ S,
                                                   int N, int M, int Nd8) {
    int b = blockIdx.z;
    long i0 = (long)blockIdx.x * 128, j0 = (long)blockIdx.y * 128;
    const unsigned short* Xb = X + (long)b * N * 128;
    const unsigned short* Yb = Y + (long)b * M * 128;
    unsigned short* Sb = S + (long)b * N * Nd8;
    int tid = threadIdx.x, wave = tid >> 6, lane = tid & 63;
    int quad = lane >> 4, rq = lane & 15;
    int rh = (wave >> 1) * 64, ch = (wave & 1) * 64;

    f4 acc[4][4];
#pragma unroll
    for (int a = 0; a < 4; ++a)
#pragma unroll
        for (int c = 0; c < 4; ++c) acc[a][c] = 0.0f;

#pragma unroll
    for (int kc = 0; kc < 4; ++kc) {
        int k0 = kc * 32 + quad * 8;
        bf8 af[4], bfr[4];
#pragma unroll
        for (int t = 0; t < 4; ++t) {
            af[t]  = *(const bf8*)(const void*)(Xb + (i0 + rh + t * 16 + rq) * 128 + k0);
            bfr[t] = *(const bf8*)(const void*)(Yb + (j0 + ch + t * 16 + rq) * 128 + k0);
        }
#pragma unroll
        for (int ti = 0; ti < 4; ++ti)
#pragma unroll
            for (int tj = 0; tj < 4; ++tj)
                acc[ti][tj] = __builtin_amdgcn_mfma_f32_16x16x32_bf16(af[ti], bfr[tj], acc[ti][tj], 0, 0, 0);
    }

#pragma unroll
    for (int ti = 0; ti < 4; ++ti)
#pragma unroll
        for (int r = 0; r < 4; ++r) {
            long gi = i0 + rh + ti * 16 + quad * 4 + r;
#pragma unroll
            for (int tj = 0; tj < 4; ++tj) {
                long gj = j0 + ch + tj * 16 + rq;
                float Ev = __expf(20.0f * acc[ti][tj][r] - 20.0f);
                Sb[gi * Nd8 + gi + gj] = f2bf_bits(Ev);
            }
        }
}

// ---------------- soft-DTW alpha-space DP (fp64) ----------------
// K=1, NWAVE=16 (Syy 12): ONE DP per 1024-thread block, 48 blocks -> 48 CUs active,
// each CU at 4 waves/SIMD. This is the only shape with both full CU count AND 4-deep
// SIMD fill (R9 proved dual-DP trades CUs for fill at a net loss: 204 us/DP effective
// on 24 CUs vs R6's 228 on 48). Per-wave issue/step halves vs K=2. Protocol = R9's
// lazy-LDS low-register variant (no raw[33]/bb[8]/cj[9] arrays; ~45 VGPR demand ->
// spill-proof at any budget). Geometry re-verified for NW=64: gb=62+32c ≡ 6 mod 8,
// BPAD=BLEN+1 (one pad step), LAG=3 with 1-round/2-entry race margins, result in vA[0].
__device__ inline double wshr1_d(double x) {  // lane l <- lane l-1, lane 0 <- 0
    i2 v = __builtin_bit_cast(i2, x);
    v.x = __builtin_amdgcn_update_dpp(0, v.x, 0x138, 0xf, 0xf, false);
    v.y = __builtin_amdgcn_update_dpp(0, v.y, 0x138, 0xf, 0xf, false);
    return __builtin_bit_cast(double, v);
}
#define DPPMAXI(x, ctrl) max((x), __builtin_amdgcn_update_dpp(0, (x), (ctrl), 0xf, 0xf, false))
__device__ inline int redmax64_i(int x) {   // full max in lane 63 (patterns >= 0)
    x = DPPMAXI(x, 0x111);  // row_shr:1
    x = DPPMAXI(x, 0x112);  // row_shr:2
    x = DPPMAXI(x, 0x114);  // row_shr:4
    x = DPPMAXI(x, 0x118);  // row_shr:8
    x = DPPMAXI(x, 0x142);  // row_bcast15
    x = DPPMAXI(x, 0x143);  // row_bcast31
    return x;
}
__device__ inline int hiw(double x) { return __builtin_bit_cast(i2, x).y; }

// K rows/lane PER WAVE; NWAVE active waves; NW = 64*K rows/wave; N = NWAVE*NW.
// w = wave id (0..15); waves w >= NWAVE idle (barrier only).
template<int K, int N, int M, int ND8, int NWAVE>
static __device__ __attribute__((always_inline))
void dp_impl(const unsigned short* __restrict__ E, long batch, int w, int lane,
             float wscale, float* __restrict__ out, char* __restrict__ smem) {
    constexpr int NW    = K * 64;              // rows handled by one wave
    constexpr int BLEN  = NW + M - 1;          // local diag count (odd; BLEN+1 ≡ 0 mod 32)
    constexpr int NCH   = (BLEN + 31) / 32;    // 32-step chunks per wave
    constexpr int BPAD  = NCH * 32;            // = BLEN+1 for all our shapes (1 pad step)
    constexpr int SLEN  = BPAD / 8;            // scale slots (one per 8 boundary entries)
    constexpr int LAG   = NW / 32 + 1;         // chunk lag between adjacent waves
    constexpr int ROUNDS = (NWAVE - 1) * LAG + NCH;

    double* bvAll = (double*)smem;                                  // (NWAVE-1) x BPAD
    int*    scAll = (int*)(smem + (size_t)(NWAVE - 1) * BPAD * 8);  // (NWAVE-1) x SLEN
    const double* bvR = bvAll + (size_t)(w > 0 ? w - 1 : 0) * BPAD;
    const int*    scR = scAll + (size_t)(w > 0 ? w - 1 : 0) * SLEN;
    double* bvW = bvAll + (size_t)(w < NWAVE - 1 ? w : 0) * BPAD;   // deref'd only if w<NWAVE-1
    int*    scW = scAll + (size_t)(w < NWAVE - 1 ? w : 0) * SLEN;

    const char* Eb = (const char*)(E + batch * N * ND8);
    unsigned off[K];
    uint4 eA[K], eB[K], eC[K], eD[K];
    double vA[K], vB[K];
#pragma unroll
    for (int r = 0; r < K; ++r) {
        off[r] = (unsigned)((((long)(w * NW + K * lane + r)) * ND8 + (long)(w * NW)) * 2);
        vA[r] = 0.0; vB[r] = 0.0;
    }
    int ls = 0;                               // accumulated log2 scale (wave-uniform)

#define EGETV(EQ, PH) __uint_as_float(((PH) & 1) ? ((&(EQ).x)[(PH) >> 1] & 0xffff0000u) \
                                                 : ((&(EQ).x)[(PH) >> 1] << 16))
#define DSTEP(W, P1, EB_, PH, S2, S1) do { \
        double b1 = wshr1_d(P1[K - 1]) + (S1); \
        double b2 = wshr1_d(W[K - 1]) + (S2); \
        double p2 = b2, p1m = b1; \
        _Pragma("unroll") \
        for (int r = 0; r < K; ++r) { \
            double told = W[r]; double c1 = P1[r]; \
            double Ed = (double)EGETV(EB_[r], PH); \
            W[r] = Ed * (p2 + p1m + c1); \
            p2 = told; p1m = c1; \
        } } while (0)

    // pow2 rescale of BOTH live diagonals, anchor 2^870 (biased 1893), every 16 steps.
#define DRESC(W, P1) do { \
        int hm = hiw(W[0]) > hiw(P1[0]) ? hiw(W[0]) : hiw(P1[0]); \
        _Pragma("unroll") \
        for (int r = 1; r < K; ++r) { \
            int h1 = hiw(W[r]), h2 = hiw(P1[r]); \
            if (h1 > hm) hm = h1; if (h2 > hm) hm = h2; } \
        hm = redmax64_i(hm); \
        int hb = __builtin_amdgcn_readlane(hm, 63); \
        if (hb > 0) { \
            int eraw2 = (hb >> 20) & 0x7ff; \
            int sh = 1893 - eraw2; \
            sh = (sh > 1020) ? 1020 : ((sh < -1020) ? -1020 : sh); \
            i2 fb; fb.x = 0; fb.y = (1023 + sh) << 20; \
            double f = __builtin_bit_cast(double, fb); \
            ls += sh; \
            _Pragma("unroll") \
            for (int r = 0; r < K; ++r) { W[r] *= f; P1[r] *= f; } \
        } } while (0)

    // lazy boundary reads (clamped like the bulk loads; clamped entries are column-masked)
#define LDP(k)  (*(const d2v*)(bvR + ((gb + (k) > BPAD - 2) ? (BPAD - 2) : (gb + (k)))))
#define LDS1(k) (bvR[(gb + (k) > BPAD - 1) ? (BPAD - 1) : (gb + (k))])
    // injection i of group G: stored_r = raw * 2^(ls_r - ls_w), masked; w0 gets the DP seed
#define INJE(G_, i_, rv) \
    (w > 0 ? ((lane == 0 && (32 * c + 8 * (G_) - 1 + (i_)) >= 0 \
                        && (32 * c + 8 * (G_) - 1 + (i_)) < M) \
                ? fmin(ldexp((rv), ls - sc5[(G_) + ((6 + (i_)) >> 3)]), 8.9e307) : 0.0) \
           : ((c == 0 && (G_) == 0 && (i_) == 0 && lane == 0) ? 1.0 : 0.0))
    // relay-pair store (entries 8G+2t, 8G+2t+1), issued right after the odd step
#define WBP(G_, t_, v0, v1) do { \
        if (w < NWAVE - 1 && lane == 63) { \
            d2v zp; zp.x = (v0); zp.y = (v1); \
            *(d2v*)(bvW + 32 * c + 8 * (G_) + 2 * (t_)) = zp; \
        } } while (0)

    // one 8-step group: lazy LDS injections (rolling window), 8 DSTEPs, interleaved relay
#define GROUP(EX, G) do { \
        d2v p01 = LDP(8 * (G) + 0); \
        d2v p23 = LDP(8 * (G) + 2); \
        double a0 = INJE(G, 0, p01.x), a1 = INJE(G, 1, p01.y); \
        double bw; \
        DSTEP(vA, vB, EX, 0, a0, a1); bw = vA[K - 1]; \
        double a2 = INJE(G, 2, p23.x), a3 = INJE(G, 3, p23.y); \
        DSTEP(vB, vA, EX, 1, a1, a2); WBP(G, 0, bw, vB[K - 1]); \
        d2v p45 = LDP(8 * (G) + 4); \
        DSTEP(vA, vB, EX, 2, a2, a3); bw = vA[K - 1]; \
        double a4 = INJE(G, 4, p45.x), a5 = INJE(G, 5, p45.y); \
        DSTEP(vB, vA, EX, 3, a3, a4); WBP(G, 1, bw, vB[K - 1]); \
        d2v p67 = LDP(8 * (G) + 6); \
        DSTEP(vA, vB, EX, 4, a4, a5); bw = vA[K - 1]; \
        double a6 = INJE(G, 6, p67.x), a7 = INJE(G, 7, p67.y); \
        DSTEP(vB, vA, EX, 5, a5, a6); WBP(G, 2, bw, vB[K - 1]); \
        double p8 = LDS1(8 * (G) + 8); \
        DSTEP(vA, vB, EX, 6, a6, a7); bw = vA[K - 1]; \
        double a8 = INJE(G, 8, p8); \
        DSTEP(vB, vA, EX, 7, a7, a8); WBP(G, 3, bw, vB[K - 1]); \
        if (w < NWAVE - 1 && lane == 63) scW[4 * c + (G)] = ls; \
    } while (0)

    for (int round = 0; round < ROUNDS; ++round) {
        const int c = round - w * LAG;         // this wave's chunk index (wave-uniform)
        if (w < NWAVE && c >= 0 && c < NCH) {
            const int gb = NW - 2 + 32 * c;    // first boundary entry (even, ≡6 mod 8)
            int sc5[5] = {0, 0, 0, 0, 0};
            if (w > 0) {
#pragma unroll
                for (int j = 0; j < 5; ++j) {
                    int s = (gb >> 3) + j; if (s > SLEN - 1) s = SLEN - 1;
                    sc5[j] = scR[s];
                }
                // ---- unified pre-anchor: fold own-field max with incoming injection
                // magnitudes (reader frame), target 2^870. Rolling max, no raw[] array.
                int hm0 = hiw(vA[0]) > hiw(vB[0]) ? hiw(vA[0]) : hiw(vB[0]);
#pragma unroll
                for (int r = 1; r < K; ++r) {
                    int h1 = hiw(vA[r]), h2 = hiw(vB[r]);
                    if (h1 > hm0) hm0 = h1; if (h2 > hm0) hm0 = h2;
                }
                hm0 = redmax64_i(hm0);
                int hbOwn = __builtin_amdgcn_readlane(hm0, 63);
                int ownEb = (hbOwn > 0) ? (hbOwn >> 20) : -1048576;
                int injEb = -1048576;
#pragma unroll
                for (int t = 0; t < 16; ++t) {
                    int idx = gb + 2 * t; if (idx > BPAD - 2) idx = BPAD - 2;
                    d2v pp = *(const d2v*)(bvR + idx);
                    int jp0 = 32 * c + 2 * t - 1, jp1 = jp0 + 1;
                    int er0 = hiw(pp.x) >> 20, er1 = hiw(pp.y) >> 20;
                    int cd0 = er0 + (ls - sc5[(6 + 2 * t) >> 3]);
                    int cd1 = er1 + (ls - sc5[(7 + 2 * t) >> 3]);
                    if (jp0 >= 0 && jp0 < M && er0 > 0 && cd0 > injEb) injEb = cd0;
                    if (jp1 >= 0 && jp1 < M && er1 > 0 && cd1 > injEb) injEb = cd1;
                }
                {
                    int idx = gb + 32; if (idx > BPAD - 1) idx = BPAD - 1;
                    double rv = bvR[idx];
                    int jp = 32 * c + 31; int er = hiw(rv) >> 20;
                    int cd = er + (ls - sc5[4]);
                    if (jp < M && er > 0 && cd > injEb) injEb = cd;
                }
                int MB = ownEb > injEb ? ownEb : injEb;
                if (MB > -1048576) {
                    int sh = 1893 - MB;
                    if (hbOwn > 0) {
                        sh = (sh > 1020) ? 1020 : ((sh < -1020) ? -1020 : sh);
                        i2 fb; fb.x = 0; fb.y = (1023 + sh) << 20;
                        double f = __builtin_bit_cast(double, fb);
#pragma unroll
                        for (int r = 0; r < K; ++r) { vA[r] *= f; vB[r] *= f; }
                    }
                    ls += sh;
                }
            }
            // ---- E loads: chunk = 32 diag entries = 64 bytes per row (4x uint4)
            if (c == 0) {
#pragma unroll
                for (int r = 0; r < K; ++r) eA[r] = *(const uint4*)(const void*)(Eb + off[r]);
            }
#pragma unroll
            for (int r = 0; r < K; ++r) {
                eB[r] = *(const uint4*)(const void*)(Eb + (off[r] + 16));
                eC[r] = *(const uint4*)(const void*)(Eb + (off[r] + 32));
                eD[r] = *(const uint4*)(const void*)(Eb + (off[r] + 48));
            }

            GROUP(eA, 0);
            GROUP(eB, 1);
            DRESC(vB, vA);
            if (c + 1 < NCH) {
#pragma unroll
                for (int r = 0; r < K; ++r) eA[r] = *(const uint4*)(const void*)(Eb + (off[r] + 64));
            }
            GROUP(eC, 2);
            GROUP(eD, 3);
            DRESC(vB, vA);
#pragma unroll
            for (int r = 0; r < K; ++r) off[r] += 64;
        }
        // publish this round's LDS writes, then sync. Raw s_barrier (no vmcnt drain):
        // in-flight E prefetches survive across the barrier.
        asm volatile("s_waitcnt lgkmcnt(0)\n\ts_barrier" ::: "memory");
    }

    if (w == NWAVE - 1 && lane == 63) {
        // A[N-1][M-1] at last-wave local diag BLEN-1 (even -> vA); the single pad step
        // (odd) scribbles vB only. Row N-1 = lane 63, r = K-1.
        double v = vA[K - 1];
        i2 vb2 = __builtin_bit_cast(i2, v);
        int eraw = (vb2.y >> 20) & 0x7ff;
        int ex = eraw - 1022;                       // v = m * 2^ex, m in [0.5,1)
        i2 mb; mb.x = vb2.x; mb.y = (vb2.y & 0x000FFFFF) | (1022 << 20);
        float mf = (float)__builtin_bit_cast(double, mb);
        if (!(mf > 0.f)) mf = 0.5f;                 // guard (cannot happen if DP sane)
        double R = -0.1 * ((double)logf(mf) + (double)(ex - ls) * 0.6931471805599453);
        atomicAdd(out, wscale * (float)R);
    }
#undef DSTEP
#undef DRESC
#undef GROUP
#undef WBP
#undef INJE
#undef LDP
#undef LDS1
#undef EGETV
}

__global__ __launch_bounds__(1024)
__attribute__((amdgpu_waves_per_eu(4, 4)))
void dp_kernel(const unsigned short* __restrict__ Sxy,
               const unsigned short* __restrict__ Sxx,
               const unsigned short* __restrict__ Syy,
               float* __restrict__ out) {
    // ONE DP per block, K=1. Max LDS = Sxx: 15 x (1088 dbl + 136 int) = 138720 B
    // (< 160 KiB; forces 1 block/CU = 16 waves = 4 waves/SIMD with a single DP).
    __shared__ __attribute__((aligned(16))) char smem[138720];
    const int w    = threadIdx.x >> 6;        // 0..15
    const int lane = threadIdx.x & 63;
    const long b   = blockIdx.x;              // one (batch, matrix) per block
    if (blockIdx.y == 0)      dp_impl<1, 1024,  768, 1792, 16>(Sxy, b, w, lane,  1.0f / 28672.0f, out, smem);
    else if (blockIdx.y == 1) dp_impl<1, 1024, 1024, 2048, 16>(Sxx, b, w, lane, -0.5f / 28672.0f, out, smem);
    else                      dp_impl<1,  768,  768, 1536, 12>(Syy, b, w, lane, -0.5f / 28672.0f, out, smem);
}

// ---------------- host launcher ----------------
extern "C" void kernel_launch(void* const* d_in, const int* in_sizes, int n_in,
                              void* d_out, int out_size, void* d_ws, size_t ws_size,
                              hipStream_t stream) {
    (void)in_sizes; (void)n_in; (void)out_size; (void)ws_size;
    const float* feats = (const float*)d_in[0];   // [16,1024,768]
    const float* targ  = (const float*)d_in[1];   // [16,768,768]
    const float* W     = (const float*)d_in[2];   // [768,128]
    const float* bias  = (const float*)d_in[3];   // [128]

    char* ws = (char*)d_ws;
    unsigned short* xbf = (unsigned short*)(ws + 0);            // 16384x128 bf16 = 4 MB
    unsigned short* ybf = (unsigned short*)(ws + 4194304);      // 12288x128 bf16 = 3 MB
    unsigned short* Wt  = (unsigned short*)(ws + 7340032);      // 128x768 bf16
    unsigned short* SxyE = (unsigned short*)(ws + 7536640);     // 16x1024x1792 bf16 E
    unsigned short* SxxE = (unsigned short*)(ws + 66256896);    // 16x1024x2048 bf16 E
    unsigned short* SyyE = (unsigned short*)(ws + 133365760);   // 16x768x1536  bf16 E

    hipMemsetAsync(d_out, 0, sizeof(float), stream);
    // zero all E streams so pad cells (invalid j) are E=0 -> alpha=0 automatically
    hipMemsetAsync(ws + 7536640, 0, 163577856, stream);

    wtrans_kernel<<<384, 256, 0, stream>>>(W, Wt);
    proj_kernel<<<128, 256, 0, stream>>>(feats, Wt, bias, xbf);
    proj_kernel<<<96, 256, 0, stream>>>(targ, Wt, bias, ybf);

    gram_kernel<<<dim3(8, 6, 16), 256, 0, stream>>>(xbf, ybf, SxyE, 1024,  768, 1792);
    gram_kernel<<<dim3(8, 8, 16), 256, 0, stream>>>(xbf, xbf, SxxE, 1024, 1024, 2048);
    gram_kernel<<<dim3(6, 6, 16), 256, 0, stream>>>(ybf, ybf, SyyE,  768,  768, 1536);

    // one DP per block: 48 blocks on 48 CUs, 16 waves each (4/SIMD)
    dp_kernel<<<dim3(16, 3), 1024, 0, stream>>>(SxyE, SxxE, SyyE, (float*)d_out);
}

// Round 13
// 530.744 us; speedup vs baseline: 1.5649x; 1.1048x over previous
//
#include <hip/hip_runtime.h>

typedef float  f4  __attribute__((ext_vector_type(4)));
typedef __bf16 bf8 __attribute__((ext_vector_type(8)));
typedef short  s8  __attribute__((ext_vector_type(8)));
typedef int    i2  __attribute__((ext_vector_type(2)));
typedef double d2v __attribute__((ext_vector_type(2)));

__device__ inline unsigned short f2bf_bits(float f) {
    unsigned u = __float_as_uint(f);
    u += 0x7fffu + ((u >> 16) & 1u);   // RNE to bf16
    return (unsigned short)(u >> 16);
}

// ---------------- W transpose + bf16 convert: Wt[n][k] = bf16(W[k][n]) ----------------
__global__ __launch_bounds__(256) void wtrans_kernel(const float* __restrict__ W,
                                                     unsigned short* __restrict__ Wt) {
    int idx = blockIdx.x * 256 + threadIdx.x;
    if (idx < 768 * 128) {
        int k = idx >> 7, n = idx & 127;
        Wt[n * 768 + k] = f2bf_bits(W[idx]);
    }
}

// ---------------- projection: Out = bf16(l2norm(In @ W + b)), 128-row tiles ----------------
__global__ __launch_bounds__(256) void proj_kernel(const float* __restrict__ In,
                                                   const unsigned short* __restrict__ Wt,
                                                   const float* __restrict__ bias,
                                                   unsigned short* __restrict__ Out) {
    int tid = threadIdx.x;
    int wave = tid >> 6, lane = tid & 63;
    int quad = lane >> 4, rq = lane & 15;
    int rh = (wave >> 1) * 64, ch = (wave & 1) * 64;
    long rowBase = (long)blockIdx.x * 128 + rh;

    f4 acc[4][4];
#pragma unroll
    for (int a = 0; a < 4; ++a)
#pragma unroll
        for (int b = 0; b < 4; ++b) acc[a][b] = 0.0f;

    for (int kc = 0; kc < 24; ++kc) {
        int k0 = kc * 32 + quad * 8;
        bf8 af[4], bfr[4];
#pragma unroll
        for (int t = 0; t < 4; ++t) {
            const float* ap = In + (rowBase + t * 16 + rq) * 768 + k0;
            f4 u0 = *(const f4*)ap;
            f4 u1 = *(const f4*)(ap + 4);
            s8 tmp;
            tmp[0] = (short)f2bf_bits(u0[0]); tmp[1] = (short)f2bf_bits(u0[1]);
            tmp[2] = (short)f2bf_bits(u0[2]); tmp[3] = (short)f2bf_bits(u0[3]);
            tmp[4] = (short)f2bf_bits(u1[0]); tmp[5] = (short)f2bf_bits(u1[1]);
            tmp[6] = (short)f2bf_bits(u1[2]); tmp[7] = (short)f2bf_bits(u1[3]);
            af[t] = __builtin_bit_cast(bf8, tmp);
            bfr[t] = *(const bf8*)(const void*)(Wt + (ch + t * 16 + rq) * 768 + k0);
        }
#pragma unroll
        for (int ti = 0; ti < 4; ++ti)
#pragma unroll
            for (int tj = 0; tj < 4; ++tj)
                acc[ti][tj] = __builtin_amdgcn_mfma_f32_16x16x32_bf16(af[ti], bfr[tj], acc[ti][tj], 0, 0, 0);
    }

    __shared__ float ssq[128];
    if (tid < 128) ssq[tid] = 0.f;
    __syncthreads();

    float b4[4];
#pragma unroll
    for (int tj = 0; tj < 4; ++tj) b4[tj] = bias[ch + tj * 16 + rq];

#pragma unroll
    for (int ti = 0; ti < 4; ++ti)
#pragma unroll
        for (int r = 0; r < 4; ++r) {
            float p = 0.f;
#pragma unroll
            for (int tj = 0; tj < 4; ++tj) {
                float z = acc[ti][tj][r] + b4[tj];
                p += z * z;
            }
            atomicAdd(&ssq[rh + ti * 16 + quad * 4 + r], p);
        }
    __syncthreads();

#pragma unroll
    for (int ti = 0; ti < 4; ++ti)
#pragma unroll
        for (int r = 0; r < 4; ++r) {
            int rowL = rh + ti * 16 + quad * 4 + r;
            float rn = rsqrtf(ssq[rowL]);
#pragma unroll
            for (int tj = 0; tj < 4; ++tj) {
                float z = (acc[ti][tj][r] + b4[tj]) * rn;
                Out[((long)blockIdx.x * 128 + rowL) * 128 + ch + tj * 16 + rq] = f2bf_bits(z);
            }
        }
}

// ------- gram: E[b][i][d=i+j] = bf16(exp((2*dot-2)*10)) = exp(-D/gamma), diagonal stream -------
__global__ __launch_bounds__(256) void gram_kernel(const unsigned short* __restrict__ X,
                                                   const unsigned short* __restrict__ Y,
                                                   unsigned short* __restrict__ S,
                                                   int N, int M, int Nd8) {
    int b = blockIdx.z;
    long i0 = (long)blockIdx.x * 128, j0 = (long)blockIdx.y * 128;
    const unsigned short* Xb = X + (long)b * N * 128;
    const unsigned short* Yb = Y + (long)b * M * 128;
    unsigned short* Sb = S + (long)b * N * Nd8;
    int tid = threadIdx.x, wave = tid >> 6, lane = tid & 63;
    int quad = lane >> 4, rq = lane & 15;
    int rh = (wave >> 1) * 64, ch = (wave & 1) * 64;

    f4 acc[4][4];
#pragma unroll
    for (int a = 0; a < 4; ++a)
#pragma unroll
        for (int c = 0; c < 4; ++c) acc[a][c] = 0.0f;

#pragma unroll
    for (int kc = 0; kc < 4; ++kc) {
        int k0 = kc * 32 + quad * 8;
        bf8 af[4], bfr[4];
#pragma unroll
        for (int t = 0; t < 4; ++t) {
            af[t]  = *(const bf8*)(const void*)(Xb + (i0 + rh + t * 16 + rq) * 128 + k0);
            bfr[t] = *(const bf8*)(const void*)(Yb + (j0 + ch + t * 16 + rq) * 128 + k0);
        }
#pragma unroll
        for (int ti = 0; ti < 4; ++ti)
#pragma unroll
            for (int tj = 0; tj < 4; ++tj)
                acc[ti][tj] = __builtin_amdgcn_mfma_f32_16x16x32_bf16(af[ti], bfr[tj], acc[ti][tj], 0, 0, 0);
    }

#pragma unroll
    for (int ti = 0; ti < 4; ++ti)
#pragma unroll
        for (int r = 0; r < 4; ++r) {
            long gi = i0 + rh + ti * 16 + quad * 4 + r;
#pragma unroll
            for (int tj = 0; tj < 4; ++tj) {
                long gj = j0 + ch + tj * 16 + rq;
                float Ev = __expf(20.0f * acc[ti][tj][r] - 20.0f);
                Sb[gi * Nd8 + gi + gj] = f2bf_bits(Ev);
            }
        }
}

// ---------------- soft-DTW alpha-space DP (fp64) ----------------
// K=4, NWAVE=4 (Syy 3): 256-thread blocks, 48 blocks on 48 CUs, 1 wave/SIMD, 64-step
// rounds (two 32-step halves per barrier). R12's boot-gated pre-anchor was WRONG
// (injection magnitude drifts vs own max by >> the 2^154 headroom across chunks;
// the per-chunk unified folding in R5/R6 was load-bearing continuously, not just at
// first contact). R13 restores the R5/R6 unified always-on pre-anchor VERBATIM per
// 32-step half; per-32-step op sequence is now exactly R6's (pre-anchor, 2 groups,
// DRESC, 2 groups, DRESC). waves_per_eu(1,1) -> 512-VGPR budget (no spill at ~270).
__device__ inline double wshr1_d(double x) {  // lane l <- lane l-1, lane 0 <- 0
    i2 v = __builtin_bit_cast(i2, x);
    v.x = __builtin_amdgcn_update_dpp(0, v.x, 0x138, 0xf, 0xf, false);
    v.y = __builtin_amdgcn_update_dpp(0, v.y, 0x138, 0xf, 0xf, false);
    return __builtin_bit_cast(double, v);
}
#define DPPMAXI(x, ctrl) max((x), __builtin_amdgcn_update_dpp(0, (x), (ctrl), 0xf, 0xf, false))
__device__ inline int redmax64_i(int x) {   // full max in lane 63 (patterns >= 0)
    x = DPPMAXI(x, 0x111);  // row_shr:1
    x = DPPMAXI(x, 0x112);  // row_shr:2
    x = DPPMAXI(x, 0x114);  // row_shr:4
    x = DPPMAXI(x, 0x118);  // row_shr:8
    x = DPPMAXI(x, 0x142);  // row_bcast15
    x = DPPMAXI(x, 0x143);  // row_bcast31
    return x;
}
__device__ inline int hiw(double x) { return __builtin_bit_cast(i2, x).y; }

// K rows/lane PER WAVE; NWAVE active waves; NW = 64*K rows/wave; N = NWAVE*NW.
template<int K, int N, int M, int ND8, int NWAVE>
static __device__ __attribute__((always_inline))
void dp_impl(const unsigned short* __restrict__ E, long batch, int w, int lane,
             float wscale, float* __restrict__ out, char* __restrict__ smem) {
    constexpr int NW    = K * 64;              // rows handled by one wave
    constexpr int BLEN  = NW + M - 1;          // local diag count (odd; BLEN+1 ≡ 0 mod 64)
    constexpr int NCH   = (BLEN + 63) / 64;    // 64-step chunks per wave
    constexpr int BPAD  = NCH * 64;            // = BLEN+1 for all our shapes (1 pad step)
    constexpr int SLEN  = BPAD / 8;            // scale slots (one per 8 boundary entries)
    constexpr int LAG   = NW / 64 + 1;         // chunk lag between adjacent waves
    constexpr int ROUNDS = (NWAVE - 1) * LAG + NCH;

    double* bvAll = (double*)smem;                                  // (NWAVE-1) x BPAD
    int*    scAll = (int*)(smem + (size_t)(NWAVE - 1) * BPAD * 8);  // (NWAVE-1) x SLEN
    const double* bvR = bvAll + (size_t)(w > 0 ? w - 1 : 0) * BPAD;
    const int*    scR = scAll + (size_t)(w > 0 ? w - 1 : 0) * SLEN;
    double* bvW = bvAll + (size_t)(w < NWAVE - 1 ? w : 0) * BPAD;   // deref'd only if w<NWAVE-1
    int*    scW = scAll + (size_t)(w < NWAVE - 1 ? w : 0) * SLEN;

    const char* Eb = (const char*)(E + batch * N * ND8);
    unsigned off[K];
    uint4 eA[K], eB[K], eC[K], eD[K], fA[K], fB[K], fC[K], fD[K];
    double vA[K], vB[K];
#pragma unroll
    for (int r = 0; r < K; ++r) {
        off[r] = (unsigned)((((long)(w * NW + K * lane + r)) * ND8 + (long)(w * NW)) * 2);
        vA[r] = 0.0; vB[r] = 0.0;
    }
    int ls = 0;                               // accumulated log2 scale (wave-uniform)

#define EGETV(EQ, PH) __uint_as_float(((PH) & 1) ? ((&(EQ).x)[(PH) >> 1] & 0xffff0000u) \
                                                 : ((&(EQ).x)[(PH) >> 1] << 16))
#define DSTEP(W, P1, EB_, PH, S2, S1) do { \
        double b1 = wshr1_d(P1[K - 1]) + (S1); \
        double b2 = wshr1_d(W[K - 1]) + (S2); \
        double p2 = b2, p1m = b1; \
        _Pragma("unroll") \
        for (int r = 0; r < K; ++r) { \
            double told = W[r]; double c1 = P1[r]; \
            double Ed = (double)EGETV(EB_[r], PH); \
            W[r] = Ed * (p2 + p1m + c1); \
            p2 = told; p1m = c1; \
        } } while (0)

    // pow2 rescale of BOTH live diagonals, anchor 2^870 (biased 1893), every 16 steps.
#define DRESC(W, P1) do { \
        int hm = hiw(W[0]) > hiw(P1[0]) ? hiw(W[0]) : hiw(P1[0]); \
        _Pragma("unroll") \
        for (int r = 1; r < K; ++r) { \
            int h1 = hiw(W[r]), h2 = hiw(P1[r]); \
            if (h1 > hm) hm = h1; if (h2 > hm) hm = h2; } \
        hm = redmax64_i(hm); \
        int hb = __builtin_amdgcn_readlane(hm, 63); \
        if (hb > 0) { \
            int eraw2 = (hb >> 20) & 0x7ff; \
            int sh = 1893 - eraw2; \
            sh = (sh > 1020) ? 1020 : ((sh < -1020) ? -1020 : sh); \
            i2 fb; fb.x = 0; fb.y = (1023 + sh) << 20; \
            double f = __builtin_bit_cast(double, fb); \
            ls += sh; \
            _Pragma("unroll") \
            for (int r = 0; r < K; ++r) { W[r] *= f; P1[r] *= f; } \
        } } while (0)

    // one 8-step group of half CC: injections from raw[] (frame ls), 8 DSTEPs, relay.
#define GROUP(EX, G, CC) do { \
        double cj[9]; \
        if (w > 0) { \
            _Pragma("unroll") \
            for (int i = 0; i <= 8; ++i) { \
                int jp = 32 * (CC) + 8 * (G) - 1 + i; \
                double v = fmin(ldexp(raw[8 * (G) + i], ls - sc5[(G) + ((6 + i) >> 3)]), 8.9e307); \
                cj[i] = (lane == 0 && jp >= 0 && jp < M) ? v : 0.0; \
            } \
        } else { \
            _Pragma("unroll") \
            for (int i = 0; i <= 8; ++i) cj[i] = 0.0; \
            if ((G) == 0 && (CC) == 0 && lane == 0) cj[0] = 1.0;  /* alpha[-1][-1]=1 seed */ \
        } \
        double bb[8]; \
        DSTEP(vA, vB, EX, 0, cj[0], cj[1]); bb[0] = vA[K - 1]; \
        DSTEP(vB, vA, EX, 1, cj[1], cj[2]); bb[1] = vB[K - 1]; \
        DSTEP(vA, vB, EX, 2, cj[2], cj[3]); bb[2] = vA[K - 1]; \
        DSTEP(vB, vA, EX, 3, cj[3], cj[4]); bb[3] = vB[K - 1]; \
        DSTEP(vA, vB, EX, 4, cj[4], cj[5]); bb[4] = vA[K - 1]; \
        DSTEP(vB, vA, EX, 5, cj[5], cj[6]); bb[5] = vB[K - 1]; \
        DSTEP(vA, vB, EX, 6, cj[6], cj[7]); bb[6] = vA[K - 1]; \
        DSTEP(vB, vA, EX, 7, cj[7], cj[8]); bb[7] = vB[K - 1]; \
        if (w < NWAVE - 1 && lane == 63) { \
            _Pragma("unroll") \
            for (int i = 0; i < 4; ++i) { \
                d2v p; p.x = bb[2 * i]; p.y = bb[2 * i + 1]; \
                *(d2v*)(bvW + 32 * (CC) + 8 * (G) + 2 * i) = p; \
            } \
            scW[4 * (CC) + (G)] = ls; \
        } } while (0)

    // one 32-step half: boundary reads raw[33], UNIFIED always-on pre-anchor (R5/R6
    // verbatim: fold own-field max with incoming injection magnitudes in reader frame,
    // target 2^870; own field zero -> direct ls jump), 4 groups, 2 DRESC.
#define HALF(CC, E0, E1, E2, E3) do { \
        const int gb = NW - 2 + 32 * (CC); \
        double raw[33]; int sc5[5] = {0, 0, 0, 0, 0}; \
        if (w > 0) { \
            _Pragma("unroll") \
            for (int i = 0; i < 16; ++i) { \
                int idx = gb + 2 * i; if (idx > BPAD - 2) idx = BPAD - 2; \
                d2v p = *(const d2v*)(bvR + idx); \
                raw[2 * i] = p.x; raw[2 * i + 1] = p.y; \
            } \
            { int idx = gb + 32; if (idx > BPAD - 1) idx = BPAD - 1; raw[32] = bvR[idx]; } \
            _Pragma("unroll") \
            for (int j = 0; j < 5; ++j) { \
                int s = (gb >> 3) + j; if (s > SLEN - 1) s = SLEN - 1; \
                sc5[j] = scR[s]; \
            } \
            int hm0 = hiw(vA[0]) > hiw(vB[0]) ? hiw(vA[0]) : hiw(vB[0]); \
            _Pragma("unroll") \
            for (int r = 1; r < K; ++r) { \
                int h1 = hiw(vA[r]), h2 = hiw(vB[r]); \
                if (h1 > hm0) hm0 = h1; if (h2 > hm0) hm0 = h2; } \
            hm0 = redmax64_i(hm0); \
            int hbOwn = __builtin_amdgcn_readlane(hm0, 63); \
            int ownEb = (hbOwn > 0) ? (hbOwn >> 20) : -1048576; \
            int injEb = -1048576; \
            _Pragma("unroll") \
            for (int i = 0; i <= 32; ++i) { \
                int jp = 32 * (CC) + i - 1; \
                int er = hiw(raw[i]) >> 20; \
                int cand = er + (ls - sc5[(6 + i) >> 3]); \
                if (jp >= 0 && jp < M && er > 0 && cand > injEb) injEb = cand; \
            } \
            int MB = ownEb > injEb ? ownEb : injEb; \
            if (MB > -1048576) { \
                int sh = 1893 - MB; \
                if (hbOwn > 0) { \
                    sh = (sh > 1020) ? 1020 : ((sh < -1020) ? -1020 : sh); \
                    i2 fb; fb.x = 0; fb.y = (1023 + sh) << 20; \
                    double f = __builtin_bit_cast(double, fb); \
                    _Pragma("unroll") \
                    for (int r = 0; r < K; ++r) { vA[r] *= f; vB[r] *= f; } \
                } \
                ls += sh; \
            } \
        } \
        GROUP(E0, 0, CC); \
        GROUP(E1, 1, CC); \
        DRESC(vB, vA); \
        GROUP(E2, 2, CC); \
        GROUP(E3, 3, CC); \
        DRESC(vB, vA); \
    } while (0)

    for (int round = 0; round < ROUNDS; ++round) {
        const int c = round - w * LAG;         // this wave's 64-step chunk index
        if (w < NWAVE && c >= 0 && c < NCH) {
            // ---- E loads: 64 diag entries = 128 bytes per row (8x uint4); both halves
            // issued upfront to batch HBM latency at 1 wave/SIMD.
            if (c == 0) {
#pragma unroll
                for (int r = 0; r < K; ++r) eA[r] = *(const uint4*)(const void*)(Eb + off[r]);
            }
#pragma unroll
            for (int r = 0; r < K; ++r) {
                eB[r] = *(const uint4*)(const void*)(Eb + (off[r] + 16));
                eC[r] = *(const uint4*)(const void*)(Eb + (off[r] + 32));
                eD[r] = *(const uint4*)(const void*)(Eb + (off[r] + 48));
                fA[r] = *(const uint4*)(const void*)(Eb + (off[r] + 64));
                fB[r] = *(const uint4*)(const void*)(Eb + (off[r] + 80));
                fC[r] = *(const uint4*)(const void*)(Eb + (off[r] + 96));
                fD[r] = *(const uint4*)(const void*)(Eb + (off[r] + 112));
            }

            HALF(2 * c,     eA, eB, eC, eD);
            if (c + 1 < NCH) {
#pragma unroll
                for (int r = 0; r < K; ++r) eA[r] = *(const uint4*)(const void*)(Eb + (off[r] + 128));
            }
            HALF(2 * c + 1, fA, fB, fC, fD);
#pragma unroll
            for (int r = 0; r < K; ++r) off[r] += 128;
        }
        // publish this round's LDS writes, then sync. Raw s_barrier (no vmcnt drain):
        // in-flight E prefetches survive across the barrier.
        asm volatile("s_waitcnt lgkmcnt(0)\n\ts_barrier" ::: "memory");
    }

    if (w == NWAVE - 1 && lane == 63) {
        // A[N-1][M-1] at last-wave local diag BLEN-1 (even -> vA); the single pad step
        // (odd) scribbles vB only. Row N-1 = lane 63, r = K-1.
        double v = vA[K - 1];
        i2 vb2 = __builtin_bit_cast(i2, v);
        int eraw = (vb2.y >> 20) & 0x7ff;
        int ex = eraw - 1022;                       // v = m * 2^ex, m in [0.5,1)
        i2 mb; mb.x = vb2.x; mb.y = (vb2.y & 0x000FFFFF) | (1022 << 20);
        float mf = (float)__builtin_bit_cast(double, mb);
        if (!(mf > 0.f)) mf = 0.5f;                 // guard (cannot happen if DP sane)
        double R = -0.1 * ((double)logf(mf) + (double)(ex - ls) * 0.6931471805599453);
        atomicAdd(out, wscale * (float)R);
    }
#undef DSTEP
#undef DRESC
#undef GROUP
#undef HALF
#undef EGETV
}

__global__ __launch_bounds__(256)
__attribute__((amdgpu_waves_per_eu(1, 1)))
void dp_kernel(const unsigned short* __restrict__ Sxy,
               const unsigned short* __restrict__ Sxx,
               const unsigned short* __restrict__ Syy,
               float* __restrict__ out) {
    // K=4: max LDS = Sxx: 3 x (1280 dbl + 160 int) = 32640 B. 256-thread blocks,
    // waves_per_eu(1,1): exactly 1 wave/SIMD resident -> 512-VGPR budget (no spill).
    __shared__ __attribute__((aligned(16))) char smem[32640];
    const int w    = threadIdx.x >> 6;        // 0..3
    const int lane = threadIdx.x & 63;
    const long b   = blockIdx.x;              // one (batch, matrix) per block
    if (blockIdx.y == 0)      dp_impl<4, 1024,  768, 1792, 4>(Sxy, b, w, lane,  1.0f / 28672.0f, out, smem);
    else if (blockIdx.y == 1) dp_impl<4, 1024, 1024, 2048, 4>(Sxx, b, w, lane, -0.5f / 28672.0f, out, smem);
    else                      dp_impl<4,  768,  768, 1536, 3>(Syy, b, w, lane, -0.5f / 28672.0f, out, smem);
}

// ---------------- host launcher ----------------
extern "C" void kernel_launch(void* const* d_in, const int* in_sizes, int n_in,
                              void* d_out, int out_size, void* d_ws, size_t ws_size,
                              hipStream_t stream) {
    (void)in_sizes; (void)n_in; (void)out_size; (void)ws_size;
    const float* feats = (const float*)d_in[0];   // [16,1024,768]
    const float* targ  = (const float*)d_in[1];   // [16,768,768]
    const float* W     = (const float*)d_in[2];   // [768,128]
    const float* bias  = (const float*)d_in[3];   // [128]

    char* ws = (char*)d_ws;
    unsigned short* xbf = (unsigned short*)(ws + 0);            // 16384x128 bf16 = 4 MB
    unsigned short* ybf = (unsigned short*)(ws + 4194304);      // 12288x128 bf16 = 3 MB
    unsigned short* Wt  = (unsigned short*)(ws + 7340032);      // 128x768 bf16
    unsigned short* SxyE = (unsigned short*)(ws + 7536640);     // 16x1024x1792 bf16 E
    unsigned short* SxxE = (unsigned short*)(ws + 66256896);    // 16x1024x2048 bf16 E
    unsigned short* SyyE = (unsigned short*)(ws + 133365760);   // 16x768x1536  bf16 E

    hipMemsetAsync(d_out, 0, sizeof(float), stream);
    // zero all E streams so pad cells (invalid j) are E=0 -> alpha=0 automatically
    hipMemsetAsync(ws + 7536640, 0, 163577856, stream);

    wtrans_kernel<<<384, 256, 0, stream>>>(W, Wt);
    proj_kernel<<<128, 256, 0, stream>>>(feats, Wt, bias, xbf);
    proj_kernel<<<96, 256, 0, stream>>>(targ, Wt, bias, ybf);

    gram_kernel<<<dim3(8, 6, 16), 256, 0, stream>>>(xbf, ybf, SxyE, 1024,  768, 1792);
    gram_kernel<<<dim3(8, 8, 16), 256, 0, stream>>>(xbf, xbf, SxxE, 1024, 1024, 2048);
    gram_kernel<<<dim3(6, 6, 16), 256, 0, stream>>>(ybf, ybf, SyyE,  768,  768, 1536);

    // one DP per block: 48 blocks on 48 CUs, 4 waves each (1/SIMD), K=4, 64-step rounds
    dp_kernel<<<dim3(16, 3), 256, 0, stream>>>(SxyE, SxxE, SyyE, (float*)d_out);
}